// Round 1
// baseline (90.186 us; speedup 1.0000x reference)
//
#include <hip/hip_runtime.h>

#define BB 64
#define FF 512
#define EE 256
#define HH 8
#define DD 32
#define LL 4

__global__ __launch_bounds__(256) void tm_fused_kernel(
    const float* __restrict__ x,      // [B,F]
    const float* __restrict__ emb_w,  // [E]
    const float* __restrict__ emb_b,  // [E]
    const float* __restrict__ q_w,    // [E,E]
    const float* __restrict__ q_b,    // [E]
    const float* __restrict__ k_w,    // [E,E]
    const float* __restrict__ k_b,    // [E]
    const float* __restrict__ v_w,    // [E,E]
    const float* __restrict__ v_b,    // [E]
    const float* __restrict__ attn_w, // [E]
    const float* __restrict__ attn_b, // [1]
    float* __restrict__ out)          // [2,B,F]
{
    const int tid = threadIdx.x;
    const int b = blockIdx.x;

    __shared__ float s_ew[EE], s_eb[EE];
    __shared__ float s_a0[HH], s_c1[HH], s_c2[HH], s_p1[HH], s_p0[HH];
    __shared__ float s_m[HH];
    __shared__ float s_hox, s_hc;

    s_ew[tid] = emb_w[tid];
    s_eb[tid] = emb_b[tid];
    __syncthreads();

    // -------- Stage 1: fold embedding into K/V/Q projections (per-column e = tid)
    float kw = 0.f, kb = 0.f, vw = 0.f, vb = 0.f, qv = 0.f;
    for (int j = 0; j < EE; ++j) {
        const float ew = s_ew[j], eb = s_eb[j];
        const float kwe = k_w[j * EE + tid];
        const float vwe = v_w[j * EE + tid];
        const float qwe = q_w[j * EE + tid];
        kw = fmaf(ew, kwe, kw);
        kb = fmaf(eb, kwe, kb);
        vw = fmaf(ew, vwe, vw);
        vb = fmaf(eb, vwe, vb);
        qv = fmaf(eb, qwe, qv);
    }
    kb += k_b[tid];
    vb += v_b[tid];
    qv += q_b[tid];
    const float aw = attn_w[tid];

    const float scale = 0.17677669529663687f; // 1/sqrt(D)

    // per-head dot products over d (heads are 32 consecutive e's)
    float t0 = qv * kw;   // -> alpha0
    float t1 = vw * kw;   // -> c1
    float t2 = vb * kw;   // -> c2
    float t3 = vw * aw;   // -> p1
    float t4 = vb * aw;   // -> p0
    for (int off = 16; off > 0; off >>= 1) {
        t0 += __shfl_xor(t0, off, 32);
        t1 += __shfl_xor(t1, off, 32);
        t2 += __shfl_xor(t2, off, 32);
        t3 += __shfl_xor(t3, off, 32);
        t4 += __shfl_xor(t4, off, 32);
    }
    if ((tid & 31) == 0) {
        const int h = tid >> 5;
        s_a0[h] = t0 * scale;
        s_c1[h] = t1;
        s_c2[h] = t2;
        s_p1[h] = t3;
        s_p0[h] = t4;
    }
    __syncthreads();

    // -------- Stage 2: scalar attention recurrence per (b, h); 32 lanes per head
    const int h = tid >> 5;
    const int lane = tid & 31;

    float xr[16];
    #pragma unroll
    for (int k = 0; k < 16; ++k)
        xr[k] = x[b * FF + lane + 32 * k];

    // sx[b] = sum_g x[b,g] (computed redundantly in every 32-group)
    float sx = 0.f;
    #pragma unroll
    for (int k = 0; k < 16; ++k) sx += xr[k];
    for (int off = 16; off > 0; off >>= 1) sx += __shfl_xor(sx, off, 32);

    float a = s_a0[h];
    const float c1 = s_c1[h], c2 = s_c2[h];
    float m = 0.f;
    for (int it = 0; it < LL; ++it) {
        float mx = -3.4e38f;
        #pragma unroll
        for (int k = 0; k < 16; ++k) mx = fmaxf(mx, a * xr[k]);
        for (int off = 16; off > 0; off >>= 1) mx = fmaxf(mx, __shfl_xor(mx, off, 32));
        float s0 = 0.f, s1 = 0.f;
        #pragma unroll
        for (int k = 0; k < 16; ++k) {
            const float e = __expf(fmaf(a, xr[k], -mx));
            s0 += e;
            s1 = fmaf(e, xr[k], s1);
        }
        for (int off = 16; off > 0; off >>= 1) {
            s0 += __shfl_xor(s0, off, 32);
            s1 += __shfl_xor(s1, off, 32);
        }
        m = s1 / s0;
        a = scale * fmaf(m, c1, c2);
    }
    if (lane == 0) s_m[h] = m;
    __syncthreads();

    if (tid == 0) {
        const float ab = attn_b[0];
        float hox = ab, hc = ab;
        for (int hh = 0; hh < HH; ++hh) {
            const float qc = fmaf(s_m[hh], s_p1[hh], s_p0[hh]);
            hox += qc;
            hc += fmaf(sx, s_p1[hh], (float)FF * s_p0[hh]) - qc;
        }
        s_hox = hox;
        s_hc = hc;
    }
    __syncthreads();

    const float hox = s_hox, hc = s_hc;
    // outputs are constant across f for each b
    out[b * FF + tid]                 = hox;
    out[b * FF + tid + 256]           = hox;
    out[BB * FF + b * FF + tid]       = hc;
    out[BB * FF + b * FF + tid + 256] = hc;
}

extern "C" void kernel_launch(void* const* d_in, const int* in_sizes, int n_in,
                              void* d_out, int out_size, void* d_ws, size_t ws_size,
                              hipStream_t stream) {
    const float* features = (const float*)d_in[0];
    const float* emb_w    = (const float*)d_in[1];
    const float* emb_b    = (const float*)d_in[2];
    const float* q_w      = (const float*)d_in[3];
    const float* q_b      = (const float*)d_in[4];
    const float* k_w      = (const float*)d_in[5];
    const float* k_b      = (const float*)d_in[6];
    const float* v_w      = (const float*)d_in[7];
    const float* v_b      = (const float*)d_in[8];
    const float* attn_w   = (const float*)d_in[9];
    const float* attn_b   = (const float*)d_in[10];
    float* out = (float*)d_out;

    tm_fused_kernel<<<dim3(BB), dim3(256), 0, stream>>>(
        features, emb_w, emb_b, q_w, q_b, k_w, k_b, v_w, v_b, attn_w, attn_b, out);
}

// Round 2
// 86.772 us; speedup vs baseline: 1.0393x; 1.0393x over previous
//
#include <hip/hip_runtime.h>

#define BB 64
#define FF 512
#define EE 256
#define HH 8
#define DD 32
#define LL 4

__global__ __launch_bounds__(256) void tm_fused_kernel(
    const float* __restrict__ x,      // [B,F]
    const float* __restrict__ emb_w,  // [E]
    const float* __restrict__ emb_b,  // [E]
    const float* __restrict__ q_w,    // [E,E]
    const float* __restrict__ q_b,    // [E]
    const float* __restrict__ k_w,    // [E,E]
    const float* __restrict__ k_b,    // [E]
    const float* __restrict__ v_w,    // [E,E]
    const float* __restrict__ v_b,    // [E]
    const float* __restrict__ attn_w, // [E]
    const float* __restrict__ attn_b, // [1]
    float* __restrict__ out)          // [2,B,F]
{
    const int tid = threadIdx.x;
    const int b = blockIdx.x;
    const int g = tid >> 6;          // row-group 0..3
    const int c = (tid & 63) << 2;   // base column 0..252

    __shared__ float s_ew[EE], s_eb[EE];
    __shared__ float s_red[5][4 * EE];   // 20 KB: per-quantity partials [group][col]
    __shared__ float s_a0[HH], s_c1[HH], s_c2[HH], s_p1[HH], s_p0[HH], s_m[HH];
    __shared__ float s_hox, s_hc;

    s_ew[tid] = emb_w[tid];
    s_eb[tid] = emb_b[tid];
    __syncthreads();

    // -------- Stage 1: fold embedding into K/V/Q projections.
    // Thread (g,c) accumulates 4 columns over rows j ≡ g (mod 4), float4 loads.
    float4 kw4 = {0,0,0,0}, kb4 = {0,0,0,0}, vw4 = {0,0,0,0},
           vb4 = {0,0,0,0}, qv4 = {0,0,0,0};
    #pragma unroll 4
    for (int j4 = 0; j4 < 64; ++j4) {
        const int j = (j4 << 2) + g;
        const float ew = s_ew[j], eb = s_eb[j];
        const float4 K = *(const float4*)(k_w + j * EE + c);
        const float4 V = *(const float4*)(v_w + j * EE + c);
        const float4 Q = *(const float4*)(q_w + j * EE + c);
        kw4.x = fmaf(ew, K.x, kw4.x); kw4.y = fmaf(ew, K.y, kw4.y);
        kw4.z = fmaf(ew, K.z, kw4.z); kw4.w = fmaf(ew, K.w, kw4.w);
        kb4.x = fmaf(eb, K.x, kb4.x); kb4.y = fmaf(eb, K.y, kb4.y);
        kb4.z = fmaf(eb, K.z, kb4.z); kb4.w = fmaf(eb, K.w, kb4.w);
        vw4.x = fmaf(ew, V.x, vw4.x); vw4.y = fmaf(ew, V.y, vw4.y);
        vw4.z = fmaf(ew, V.z, vw4.z); vw4.w = fmaf(ew, V.w, vw4.w);
        vb4.x = fmaf(eb, V.x, vb4.x); vb4.y = fmaf(eb, V.y, vb4.y);
        vb4.z = fmaf(eb, V.z, vb4.z); vb4.w = fmaf(eb, V.w, vb4.w);
        qv4.x = fmaf(eb, Q.x, qv4.x); qv4.y = fmaf(eb, Q.y, qv4.y);
        qv4.z = fmaf(eb, Q.z, qv4.z); qv4.w = fmaf(eb, Q.w, qv4.w);
    }
    const int ri = (g << 8) + c;
    *(float4*)&s_red[0][ri] = kw4;
    *(float4*)&s_red[1][ri] = kb4;
    *(float4*)&s_red[2][ri] = vw4;
    *(float4*)&s_red[3][ri] = vb4;
    *(float4*)&s_red[4][ri] = qv4;
    __syncthreads();

    // Reassemble per-column values (col = tid), 4-way group reduction.
    float kw = s_red[0][tid] + s_red[0][256 + tid] + s_red[0][512 + tid] + s_red[0][768 + tid];
    float kb = s_red[1][tid] + s_red[1][256 + tid] + s_red[1][512 + tid] + s_red[1][768 + tid];
    float vw = s_red[2][tid] + s_red[2][256 + tid] + s_red[2][512 + tid] + s_red[2][768 + tid];
    float vb = s_red[3][tid] + s_red[3][256 + tid] + s_red[3][512 + tid] + s_red[3][768 + tid];
    float qv = s_red[4][tid] + s_red[4][256 + tid] + s_red[4][512 + tid] + s_red[4][768 + tid];
    kb += k_b[tid];
    vb += v_b[tid];
    qv += q_b[tid];
    const float aw = attn_w[tid];

    const float scale = 0.17677669529663687f; // 1/sqrt(D)

    // per-head dot products over d (heads are 32 consecutive e's)
    float t0 = qv * kw;   // -> alpha0
    float t1 = vw * kw;   // -> c1
    float t2 = vb * kw;   // -> c2
    float t3 = vw * aw;   // -> p1
    float t4 = vb * aw;   // -> p0
    for (int off = 16; off > 0; off >>= 1) {
        t0 += __shfl_xor(t0, off, 32);
        t1 += __shfl_xor(t1, off, 32);
        t2 += __shfl_xor(t2, off, 32);
        t3 += __shfl_xor(t3, off, 32);
        t4 += __shfl_xor(t4, off, 32);
    }
    if ((tid & 31) == 0) {
        const int h = tid >> 5;
        s_a0[h] = t0 * scale;
        s_c1[h] = t1;
        s_c2[h] = t2;
        s_p1[h] = t3;
        s_p0[h] = t4;
    }
    __syncthreads();

    // -------- Stage 2: scalar attention recurrence per (b, h); 32 lanes per head.
    // All reductions are permutation-invariant over (lane, k) -> float4 loads OK.
    const int h = tid >> 5;
    const int lane = tid & 31;

    float xr[16];
    #pragma unroll
    for (int k = 0; k < 4; ++k) {
        const float4 xv = *(const float4*)(x + b * FF + (lane << 2) + (k << 7));
        xr[4 * k + 0] = xv.x; xr[4 * k + 1] = xv.y;
        xr[4 * k + 2] = xv.z; xr[4 * k + 3] = xv.w;
    }

    float sx = 0.f;
    #pragma unroll
    for (int k = 0; k < 16; ++k) sx += xr[k];
    for (int off = 16; off > 0; off >>= 1) sx += __shfl_xor(sx, off, 32);

    float a = s_a0[h];
    const float c1 = s_c1[h], c2 = s_c2[h];
    float m = 0.f;
    for (int it = 0; it < LL; ++it) {
        float p[16];
        float mx = -3.4e38f;
        #pragma unroll
        for (int k = 0; k < 16; ++k) {
            p[k] = a * xr[k];
            mx = fmaxf(mx, p[k]);
        }
        for (int off = 16; off > 0; off >>= 1) mx = fmaxf(mx, __shfl_xor(mx, off, 32));
        float s0 = 0.f, s1 = 0.f;
        #pragma unroll
        for (int k = 0; k < 16; ++k) {
            const float e = __expf(p[k] - mx);
            s0 += e;
            s1 = fmaf(e, xr[k], s1);
        }
        for (int off = 16; off > 0; off >>= 1) {
            s0 += __shfl_xor(s0, off, 32);
            s1 += __shfl_xor(s1, off, 32);
        }
        m = s1 / s0;
        a = scale * fmaf(m, c1, c2);
    }
    if (lane == 0) s_m[h] = m;
    __syncthreads();

    if (tid == 0) {
        const float ab = attn_b[0];
        float hox = ab, hc = ab;
        for (int hh = 0; hh < HH; ++hh) {
            const float qc = fmaf(s_m[hh], s_p1[hh], s_p0[hh]);
            hox += qc;
            hc += fmaf(sx, s_p1[hh], (float)FF * s_p0[hh]) - qc;
        }
        s_hox = hox;
        s_hc = hc;
    }
    __syncthreads();

    const float hox = s_hox, hc = s_hc;
    // outputs are constant across f for each b
    out[b * FF + tid]                 = hox;
    out[b * FF + tid + 256]           = hox;
    out[BB * FF + b * FF + tid]       = hc;
    out[BB * FF + b * FF + tid + 256] = hc;
}

extern "C" void kernel_launch(void* const* d_in, const int* in_sizes, int n_in,
                              void* d_out, int out_size, void* d_ws, size_t ws_size,
                              hipStream_t stream) {
    const float* features = (const float*)d_in[0];
    const float* emb_w    = (const float*)d_in[1];
    const float* emb_b    = (const float*)d_in[2];
    const float* q_w      = (const float*)d_in[3];
    const float* q_b      = (const float*)d_in[4];
    const float* k_w      = (const float*)d_in[5];
    const float* k_b      = (const float*)d_in[6];
    const float* v_w      = (const float*)d_in[7];
    const float* v_b      = (const float*)d_in[8];
    const float* attn_w   = (const float*)d_in[9];
    const float* attn_b   = (const float*)d_in[10];
    float* out = (float*)d_out;

    tm_fused_kernel<<<dim3(BB), dim3(256), 0, stream>>>(
        features, emb_w, emb_b, q_w, q_b, k_w, k_b, v_w, v_b, attn_w, attn_b, out);
}

// Round 4
// 83.542 us; speedup vs baseline: 1.0795x; 1.0387x over previous
//
#include <hip/hip_runtime.h>

#define BB 64
#define FF 512
#define EE 256
#define HH 8
#define DD 32
#define LL 4
#define NG 16   // stage-1 row groups (16 waves)

__global__ __launch_bounds__(1024) void tm_fused_kernel(
    const float* __restrict__ x,      // [B,F]
    const float* __restrict__ emb_w,  // [E]
    const float* __restrict__ emb_b,  // [E]
    const float* __restrict__ q_w,    // [E,E]
    const float* __restrict__ q_b,    // [E]
    const float* __restrict__ k_w,    // [E,E]
    const float* __restrict__ k_b,    // [E]  (dead: cancels in softmax)
    const float* __restrict__ v_w,    // [E,E]
    const float* __restrict__ v_b,    // [E]
    const float* __restrict__ attn_w, // [E]
    const float* __restrict__ attn_b, // [1]
    float* __restrict__ out)          // [2,B,F]
{
    const int tid = threadIdx.x;
    const int b = blockIdx.x;
    const int g = tid >> 6;          // row-group 0..15 (== wave id)
    const int c = (tid & 63) << 2;   // base column 0..252
    const float scale = 0.17677669529663687f; // 1/sqrt(D)

    __shared__ float s_ew[EE], s_eb[EE];
    __shared__ float s_red[4][NG * EE];   // 64 KB partials [quantity][group][col]
    __shared__ float s_a0[HH], s_c1[HH], s_c2[HH], s_p1[HH], s_p0[HH], s_m[HH];
    __shared__ float s_hox, s_hc;

    // Early: stage-2 threads prefetch their feature registers + attn_w.
    float xr[16];
    float aw = 0.f;
    if (tid < 256) {
        const int lane = tid & 31;
        #pragma unroll
        for (int k = 0; k < 4; ++k) {
            const float4 xv = *(const float4*)(x + b * FF + (lane << 2) + (k << 7));
            xr[4 * k + 0] = xv.x; xr[4 * k + 1] = xv.y;
            xr[4 * k + 2] = xv.z; xr[4 * k + 3] = xv.w;
        }
        aw = attn_w[tid];
        s_ew[tid] = emb_w[tid];
        s_eb[tid] = emb_b[tid];
    }
    __syncthreads();

    // -------- Stage 1: fold embedding into K/V/Q projections.
    // Thread (g,c): rows j ≡ g (mod 16), 4 columns, float4 loads. 16 waves hide latency.
    // kb = emb_b@k_w + k_b is DEAD: it shifts scores by a g-constant that softmax cancels.
    float4 kw4 = {0,0,0,0}, vw4 = {0,0,0,0}, vb4 = {0,0,0,0}, qv4 = {0,0,0,0};
    #pragma unroll 4
    for (int j4 = 0; j4 < NG; ++j4) {
        const int j = (j4 << 4) + g;
        const float ew = s_ew[j], eb = s_eb[j];   // wave-uniform broadcast
        const float4 K = *(const float4*)(k_w + j * EE + c);
        const float4 V = *(const float4*)(v_w + j * EE + c);
        const float4 Q = *(const float4*)(q_w + j * EE + c);
        kw4.x = fmaf(ew, K.x, kw4.x); kw4.y = fmaf(ew, K.y, kw4.y);
        kw4.z = fmaf(ew, K.z, kw4.z); kw4.w = fmaf(ew, K.w, kw4.w);
        vw4.x = fmaf(ew, V.x, vw4.x); vw4.y = fmaf(ew, V.y, vw4.y);
        vw4.z = fmaf(ew, V.z, vw4.z); vw4.w = fmaf(ew, V.w, vw4.w);
        vb4.x = fmaf(eb, V.x, vb4.x); vb4.y = fmaf(eb, V.y, vb4.y);
        vb4.z = fmaf(eb, V.z, vb4.z); vb4.w = fmaf(eb, V.w, vb4.w);
        qv4.x = fmaf(eb, Q.x, qv4.x); qv4.y = fmaf(eb, Q.y, qv4.y);
        qv4.z = fmaf(eb, Q.z, qv4.z); qv4.w = fmaf(eb, Q.w, qv4.w);
    }
    const int ri = g * EE + c;
    *(float4*)&s_red[0][ri] = kw4;
    *(float4*)&s_red[1][ri] = vw4;
    *(float4*)&s_red[2][ri] = vb4;
    *(float4*)&s_red[3][ri] = qv4;
    __syncthreads();

    if (tid < 256) {
        // Reassemble per-column values (col = tid): 16-way group reduction.
        float kw = 0.f, vw = 0.f, vb = 0.f, qv = 0.f;
        #pragma unroll
        for (int gg = 0; gg < NG; ++gg) {
            kw += s_red[0][gg * EE + tid];
            vw += s_red[1][gg * EE + tid];
            vb += s_red[2][gg * EE + tid];
            qv += s_red[3][gg * EE + tid];
        }
        vb += v_b[tid];
        qv += q_b[tid];

        // per-head dot products over d (heads = 32 consecutive e's)
        float t0 = qv * kw;   // -> alpha0
        float t1 = vw * kw;   // -> c1
        float t2 = vb * kw;   // -> c2
        float t3 = vw * aw;   // -> p1
        float t4 = vb * aw;   // -> p0
        for (int off = 16; off > 0; off >>= 1) {
            t0 += __shfl_xor(t0, off, 32);
            t1 += __shfl_xor(t1, off, 32);
            t2 += __shfl_xor(t2, off, 32);
            t3 += __shfl_xor(t3, off, 32);
            t4 += __shfl_xor(t4, off, 32);
        }
        if ((tid & 31) == 0) {
            const int h = tid >> 5;
            s_a0[h] = t0 * scale;
            s_c1[h] = t1;
            s_c2[h] = t2;
            s_p1[h] = t3;
            s_p0[h] = t4;
        }
    }
    __syncthreads();

    // -------- Stage 2: scalar attention recurrence per (b,h); 32 lanes per head.
    float sx = 0.f;
    if (tid < 256) {
        const int h = tid >> 5;
        const int lane = tid & 31;

        #pragma unroll
        for (int k = 0; k < 16; ++k) sx += xr[k];
        for (int off = 16; off > 0; off >>= 1) sx += __shfl_xor(sx, off, 32);

        float a = s_a0[h];
        const float c1 = s_c1[h], c2 = s_c2[h];
        float m = 0.f;
        for (int it = 0; it < LL; ++it) {
            float mx = -3.4e38f;
            #pragma unroll
            for (int k = 0; k < 16; ++k) mx = fmaxf(mx, a * xr[k]);
            for (int off = 16; off > 0; off >>= 1) mx = fmaxf(mx, __shfl_xor(mx, off, 32));
            float s0 = 0.f, s1 = 0.f;
            #pragma unroll
            for (int k = 0; k < 16; ++k) {
                const float e = __expf(fmaf(a, xr[k], -mx));
                s0 += e;
                s1 = fmaf(e, xr[k], s1);
            }
            for (int off = 16; off > 0; off >>= 1) {
                s0 += __shfl_xor(s0, off, 32);
                s1 += __shfl_xor(s1, off, 32);
            }
            m = s1 / s0;
            a = scale * fmaf(m, c1, c2);
        }
        if (lane == 0) s_m[h] = m;
        if (tid == 0) s_hox = sx;   // stash sx for the combiner
    }
    __syncthreads();

    if (tid == 0) {
        const float ab = attn_b[0];
        const float sxv = s_hox;
        float hox = ab, hc = ab;
        for (int hh = 0; hh < HH; ++hh) {
            const float qc = fmaf(s_m[hh], s_p1[hh], s_p0[hh]);
            hox += qc;
            hc += fmaf(sxv, s_p1[hh], (float)FF * s_p0[hh]) - qc;
        }
        s_hox = hox;
        s_hc = hc;
    }
    __syncthreads();

    // outputs are constant across f for each b; 1024 threads write 1024 values
    if (tid < FF) {
        out[b * FF + tid] = s_hox;
    } else {
        out[BB * FF + b * FF + (tid - FF)] = s_hc;
    }
}

extern "C" void kernel_launch(void* const* d_in, const int* in_sizes, int n_in,
                              void* d_out, int out_size, void* d_ws, size_t ws_size,
                              hipStream_t stream) {
    const float* features = (const float*)d_in[0];
    const float* emb_w    = (const float*)d_in[1];
    const float* emb_b    = (const float*)d_in[2];
    const float* q_w      = (const float*)d_in[3];
    const float* q_b      = (const float*)d_in[4];
    const float* k_w      = (const float*)d_in[5];
    const float* k_b      = (const float*)d_in[6];
    const float* v_w      = (const float*)d_in[7];
    const float* v_b      = (const float*)d_in[8];
    const float* attn_w   = (const float*)d_in[9];
    const float* attn_b   = (const float*)d_in[10];
    float* out = (float*)d_out;

    tm_fused_kernel<<<dim3(BB), dim3(1024), 0, stream>>>(
        features, emb_w, emb_b, q_w, q_b, k_w, k_b, v_w, v_b, attn_w, attn_b, out);
}